// Round 4
// baseline (284.508 us; speedup 1.0000x reference)
//
#include <hip/hip_runtime.h>
#include <stdint.h>

#define N_TOK 8192
#define C_DIM 768
#define E_NUM 8
#define BK 32
#define NT (C_DIM / BK)   // 24 K-tiles

typedef short short8 __attribute__((ext_vector_type(8)));
typedef __bf16 bf16x8 __attribute__((ext_vector_type(8)));
typedef float f32x4 __attribute__((ext_vector_type(4)));

static __device__ __forceinline__ unsigned short f2bf(float f) {
    unsigned u = __float_as_uint(f);
    unsigned r = u + 0x7FFFu + ((u >> 16) & 1u);
    return (unsigned short)(r >> 16);
}
static __device__ __forceinline__ float bf2f(unsigned short h) {
    return __uint_as_float(((unsigned)h) << 16);
}

// ---------------- convert x: fp32 -> bf16 ----------------
__global__ void convert_x_kernel(const float* __restrict__ x, unsigned short* __restrict__ xb, int n4) {
    int i = blockIdx.x * blockDim.x + threadIdx.x;
    if (i >= n4) return;
    const float4 v = *reinterpret_cast<const float4*>(x + (size_t)i * 4);
    ushort4 o;
    o.x = f2bf(v.x); o.y = f2bf(v.y); o.z = f2bf(v.z); o.w = f2bf(v.w);
    *reinterpret_cast<ushort4*>(xb + (size_t)i * 4) = o;
}

// ------------- transpose+convert weights: Wt[m][o][i] = W[m][i][o], bf16 -------------
__global__ void wtrans_kernel(const float* __restrict__ wfc, const float* __restrict__ wpj,
                              const float* __restrict__ w1, const float* __restrict__ w2,
                              unsigned short* __restrict__ Wt) {
    __shared__ float tile[32][33];
    const int m = blockIdx.z;
    const float* src = (m == 0) ? wfc : (m == 1) ? wpj
                     : (m < 10) ? (w1 + (size_t)(m - 2) * C_DIM * C_DIM)
                                : (w2 + (size_t)(m - 10) * C_DIM * C_DIM);
    const int i0 = blockIdx.y * 32;
    const int o0 = blockIdx.x * 32;
    #pragma unroll
    for (int rr = 0; rr < 32; rr += 8)
        tile[threadIdx.y + rr][threadIdx.x] = src[(size_t)(i0 + threadIdx.y + rr) * C_DIM + o0 + threadIdx.x];
    __syncthreads();
    unsigned short* dst = Wt + (size_t)m * C_DIM * C_DIM;
    #pragma unroll
    for (int rr = 0; rr < 32; rr += 8) {
        int o = o0 + threadIdx.y + rr;
        dst[(size_t)o * C_DIM + i0 + threadIdx.x] = f2bf(tile[threadIdx.x][threadIdx.y + rr]);
    }
}

// ---------------- router pass 1: fp32 logits, sigmoid, top-2 (no atomics) ----------------
__global__ void router_kernel(const float* __restrict__ x, const float* __restrict__ rw,
                              const float* __restrict__ bias,
                              float* __restrict__ topk_w, int* __restrict__ eids) {
    const int wave = threadIdx.x >> 6;
    const int lane = threadIdx.x & 63;
    const int n = blockIdx.x * 4 + wave;
    const float* xp = x + (size_t)n * C_DIM + lane * 12;
    float xv[12];
    #pragma unroll
    for (int j = 0; j < 12; j++) xv[j] = xp[j];
    float acc[E_NUM];
    #pragma unroll
    for (int e = 0; e < E_NUM; e++) acc[e] = 0.f;
    #pragma unroll
    for (int e = 0; e < E_NUM; e++) {
        const float* wp = rw + (size_t)e * C_DIM + lane * 12;
        #pragma unroll
        for (int j = 0; j < 12; j++) acc[e] += xv[j] * wp[j];
    }
    #pragma unroll
    for (int e = 0; e < E_NUM; e++) {
        #pragma unroll
        for (int off = 32; off > 0; off >>= 1) acc[e] += __shfl_xor(acc[e], off, 64);
    }
    if (lane == 0) {
        float sc[E_NUM];
        #pragma unroll
        for (int e = 0; e < E_NUM; e++) sc[e] = 1.f / (1.f + expf(-acc[e]));
        int e0 = 0; float best = -1e30f;
        #pragma unroll
        for (int e = 0; e < E_NUM; e++) { float v = sc[e] + bias[e]; if (v > best) { best = v; e0 = e; } }
        int e1 = -1; float best1 = -1e30f;
        #pragma unroll
        for (int e = 0; e < E_NUM; e++) { if (e == e0) continue; float v = sc[e] + bias[e]; if (v > best1) { best1 = v; e1 = e; } }
        float w0 = sc[e0], w1 = sc[e1];
        float s = w0 + w1 + 1e-20f;
        w0 /= s; w1 /= s;
        topk_w[n * 2] = w0; topk_w[n * 2 + 1] = w1;
        eids[n * 2] = e0; eids[n * 2 + 1] = e1;
    }
}

// ---------------- router pass 2: per-expert compaction (deterministic) ----------------
__global__ __launch_bounds__(1024) void bucketize_kernel(const int* __restrict__ eids,
                                                         int* __restrict__ counts,
                                                         int* __restrict__ buckets) {
    const int e = blockIdx.x;
    const int t = threadIdx.x;
    const int wv = t >> 6, lane = t & 63;
    __shared__ int wave_tot[16];
    int running = 0;
    for (int start = 0; start < 2 * N_TOK; start += 1024) {
        const int i = start + t;
        const int f = (eids[i] == e) ? 1 : 0;
        unsigned long long mask = __ballot(f);
        int pre = __popcll(mask & ((1ull << lane) - 1ull));
        if (lane == 0) wave_tot[wv] = __popcll(mask);
        __syncthreads();
        int wbase = 0, tot = 0;
        #pragma unroll
        for (int j = 0; j < 16; j++) { int c = wave_tot[j]; tot += c; if (j < wv) wbase += c; }
        if (f) buckets[e * N_TOK + running + wbase + pre] = i;
        running += tot;
        __syncthreads();
    }
    if (t == 0) counts[e] = running;
}

// ============ 256x256 bf16 MFMA GEMM, BK=32, 8 waves, 4-buffer ring, counted vmcnt ============
// z in [0,8]: z<8 = expert (rows gathered via buckets), z==8 = shared (direct rows).
// PHASE 0 (fc):   A = xb;  epi relu^2 -> Hsh[n] (shared) / H[ent] (expert), bf16
// PHASE 1 (proj): A = Hsh / H-gathered;  epi -> out[n] fp32 (shared) / Y[ent] bf16 (expert)
// LDS per buffer: A[256 rows][32k] @0, B[256 cols][32k] @8192 (ushort offsets); 4 buffers = 128 KiB.
// Swizzle (zero-conflict, verified r3): 16B slot' = slot ^ ((row>>1)&3); linear gload_lds dest +
// pre-swizzled global source + swizzled ds_read.
#define GLOAD_LDS(g, l) __builtin_amdgcn_global_load_lds((const __attribute__((address_space(1))) void*)(g), (__attribute__((address_space(3))) void*)(l), 16, 0, 0)
#define WAITVM(n) asm volatile("s_waitcnt vmcnt(" #n ")" ::: "memory")
#define SCHEDB() __builtin_amdgcn_sched_barrier(0)
#define BAR() __builtin_amdgcn_s_barrier()

template <int PHASE>
__global__ __launch_bounds__(512, 2) void gemm256_kernel(const unsigned short* __restrict__ Adir,
                                                         const unsigned short* __restrict__ Agat,
                                                         const unsigned short* __restrict__ WtAll,
                                                         void* __restrict__ dstDir,
                                                         unsigned short* __restrict__ dstGat,
                                                         const int* __restrict__ counts,
                                                         const int* __restrict__ buckets) {
    const int z = blockIdx.z;
    const bool sh = (z == E_NUM);
    const int rows = sh ? N_TOK : counts[z];
    const int r0 = blockIdx.x * 256;
    if (r0 >= rows) return;
    const int c0 = blockIdx.y * 256;

    __shared__ __align__(16) unsigned short lds[4 * 16384];   // 128 KiB

    const int t = threadIdx.x;
    const int lane = t & 63;
    const int wv = t >> 6;

    const int widx = sh ? (PHASE == 0 ? 0 : 1) : (PHASE == 0 ? 2 + z : 10 + z);
    const unsigned short* Bmat = WtAll + (size_t)widx * C_DIM * C_DIM;
    const int* bk = buckets + z * N_TOK;

    // ---- staging setup: thread t covers LDS row t>>2 (and +128), 16B slot t&3 (linear dest) ----
    const int srow = t >> 2;                                   // 0..127
    const int ssw = (((t & 3) ^ ((t >> 3) & 3)) * 8);          // pre-swizzled source slot (elems)
    int gr0, gr1;
    const unsigned short* Asrc;
    if (sh) {
        Asrc = Adir; gr0 = r0 + srow; gr1 = r0 + 128 + srow;
    } else {
        Asrc = Agat;
        int p0 = r0 + srow, p1 = r0 + 128 + srow;
        int e0 = bk[p0 < rows ? p0 : 0];
        int e1 = bk[p1 < rows ? p1 : 0];
        gr0 = (PHASE == 0) ? (e0 >> 1) : e0;
        gr1 = (PHASE == 0) ? (e1 >> 1) : e1;
    }
    const unsigned short* ap0 = Asrc + (size_t)gr0 * C_DIM + ssw;
    const unsigned short* ap1 = Asrc + (size_t)gr1 * C_DIM + ssw;
    const unsigned short* bp0 = Bmat + (size_t)(c0 + srow) * C_DIM + ssw;
    const unsigned short* bp1 = Bmat + (size_t)(c0 + 128 + srow) * C_DIM + ssw;

    auto STAGE = [&](int kt) {
        unsigned short* d = lds + (kt & 3) * 16384 + t * 8;
        const int ko = kt * BK;
        GLOAD_LDS(ap0 + ko, d);             // A rows 0..127
        GLOAD_LDS(ap1 + ko, d + 4096);      // A rows 128..255
        GLOAD_LDS(bp0 + ko, d + 8192);      // B cols 0..127
        GLOAD_LDS(bp1 + ko, d + 12288);     // B cols 128..255
    };

    // ---- compute setup: wave (wm,wn) owns 128x64 output ----
    const int wm = wv >> 2, wn = wv & 3;
    const int fr = lane & 15, fq = lane >> 4;
    const int rsw = ((fq ^ ((fr >> 1) & 3)) * 8);              // swizzled read slot (elems)
    const int abase = (wm * 128 + fr) * 32 + rsw;              // + m*512
    const int bbase = 8192 + (wn * 64 + fr) * 32 + rsw;        // + n*512

    f32x4 acc[8][4];
    #pragma unroll
    for (int m = 0; m < 8; m++)
        #pragma unroll
        for (int n = 0; n < 4; n++) acc[m][n] = (f32x4){0.f, 0.f, 0.f, 0.f};

    STAGE(0); STAGE(1); STAGE(2);                              // depth-3 prologue (12/wave)

    for (int kt = 0; kt < NT; ++kt) {
        if (kt + 3 < NT) { STAGE(kt + 3); WAITVM(12); }
        else if (kt + 3 == NT) { WAITVM(8); }
        else if (kt + 2 == NT) { WAITVM(4); }
        else { WAITVM(0); }
        BAR();          // tile kt present in LDS for all waves
        SCHEDB();       // nothing from compute may cross above this point
        const unsigned short* buf = lds + (kt & 3) * 16384;
        short8 bfrag[4];
        #pragma unroll
        for (int n = 0; n < 4; n++)
            bfrag[n] = *reinterpret_cast<const short8*>(buf + bbase + n * 512);
        __builtin_amdgcn_s_setprio(1);
        #pragma unroll
        for (int m = 0; m < 8; m++) {
            short8 afr = *reinterpret_cast<const short8*>(buf + abase + m * 512);
            #pragma unroll
            for (int n = 0; n < 4; n++)
                acc[m][n] = __builtin_amdgcn_mfma_f32_16x16x32_bf16(
                    __builtin_bit_cast(bf16x8, afr), __builtin_bit_cast(bf16x8, bfrag[n]), acc[m][n], 0, 0, 0);
        }
        __builtin_amdgcn_s_setprio(0);
        SCHEDB();       // nothing from compute may sink below
        BAR();          // all waves done reading buf[kt&3]; next STAGE may overwrite (kt+1)+3 ≡ kt-... safe
    }

    // ---- epilogue ----
    const int orow = r0 + wm * 128;   // + m*16 + fq*4 + rr
    const int ocol = c0 + wn * 64;    // + n*16 + fr
    if (sh) {
        if constexpr (PHASE == 0) {
            unsigned short* Hd = (unsigned short*)dstDir;
            #pragma unroll
            for (int m = 0; m < 8; m++)
                #pragma unroll
                for (int rr = 0; rr < 4; rr++) {
                    size_t base = (size_t)(orow + m * 16 + fq * 4 + rr) * C_DIM;
                    #pragma unroll
                    for (int n = 0; n < 4; n++) {
                        float v = acc[m][n][rr];
                        float rl = v > 0.f ? v : 0.f;
                        Hd[base + ocol + n * 16 + fr] = f2bf(rl * rl);
                    }
                }
        } else {
            float* od = (float*)dstDir;
            #pragma unroll
            for (int m = 0; m < 8; m++)
                #pragma unroll
                for (int rr = 0; rr < 4; rr++) {
                    size_t base = (size_t)(orow + m * 16 + fq * 4 + rr) * C_DIM;
                    #pragma unroll
                    for (int n = 0; n < 4; n++)
                        od[base + ocol + n * 16 + fr] = acc[m][n][rr];
                }
        }
    } else {
        #pragma unroll
        for (int m = 0; m < 8; m++)
            #pragma unroll
            for (int rr = 0; rr < 4; rr++) {
                int pos = orow + m * 16 + fq * 4 + rr;
                if (pos < rows) {
                    int ent = bk[pos];
                    size_t base = (size_t)ent * C_DIM;
                    #pragma unroll
                    for (int n = 0; n < 4; n++) {
                        float v = acc[m][n][rr];
                        if (PHASE == 0) {
                            float rl = v > 0.f ? v : 0.f;
                            dstGat[base + ocol + n * 16 + fr] = f2bf(rl * rl);
                        } else {
                            dstGat[base + ocol + n * 16 + fr] = f2bf(v);
                        }
                    }
                }
            }
    }
}

// ---------------- combine: out += w0*Y[n,0] + w1*Y[n,1] ----------------
__global__ void combine_kernel(float* __restrict__ out, const unsigned short* __restrict__ Y,
                               const float* __restrict__ tw) {
    int idx = blockIdx.x * blockDim.x + threadIdx.x;
    const int per_row = C_DIM / 4;
    if (idx >= N_TOK * per_row) return;
    int n = idx / per_row;
    int c = (idx % per_row) * 4;
    float w0 = tw[n * 2], w1 = tw[n * 2 + 1];
    const ushort4 a = *reinterpret_cast<const ushort4*>(Y + (size_t)(n * 2) * C_DIM + c);
    const ushort4 b = *reinterpret_cast<const ushort4*>(Y + (size_t)(n * 2 + 1) * C_DIM + c);
    float4* op = reinterpret_cast<float4*>(out + (size_t)n * C_DIM + c);
    float4 o = *op;
    o.x += w0 * bf2f(a.x) + w1 * bf2f(b.x);
    o.y += w0 * bf2f(a.y) + w1 * bf2f(b.y);
    o.z += w0 * bf2f(a.z) + w1 * bf2f(b.z);
    o.w += w0 * bf2f(a.w) + w1 * bf2f(b.w);
    *op = o;
}

extern "C" void kernel_launch(void* const* d_in, const int* in_sizes, int n_in,
                              void* d_out, int out_size, void* d_ws, size_t ws_size,
                              hipStream_t stream) {
    const float* x   = (const float*)d_in[0];
    const float* wfc = (const float*)d_in[1];
    const float* wpj = (const float*)d_in[2];
    const float* w1  = (const float*)d_in[3];
    const float* w2  = (const float*)d_in[4];
    const float* rw  = (const float*)d_in[5];
    const float* bias= (const float*)d_in[6];
    float* out = (float*)d_out;

    char* ws = (char*)d_ws;
    size_t off = 0;
    auto alloc = [&](size_t bytes) { void* p = ws + off; off += (bytes + 255) & ~(size_t)255; return p; };
    unsigned short* xb   = (unsigned short*)alloc((size_t)N_TOK * C_DIM * 2);
    unsigned short* Wt   = (unsigned short*)alloc((size_t)18 * C_DIM * C_DIM * 2);
    unsigned short* H    = (unsigned short*)alloc((size_t)N_TOK * 2 * C_DIM * 2);  // expert hidden, by entry
    unsigned short* Hsh  = (unsigned short*)alloc((size_t)N_TOK * C_DIM * 2);      // shared hidden
    unsigned short* Y    = (unsigned short*)alloc((size_t)N_TOK * 2 * C_DIM * 2);  // expert out, by entry
    float* topk_w        = (float*)alloc((size_t)N_TOK * 2 * 4);
    int* counts          = (int*)alloc(256);
    int* buckets         = (int*)alloc((size_t)E_NUM * N_TOK * 4);
    int* eids            = (int*)alloc((size_t)2 * N_TOK * 4);

    convert_x_kernel<<<(N_TOK * C_DIM / 4 + 255) / 256, 256, 0, stream>>>(x, xb, N_TOK * C_DIM / 4);
    wtrans_kernel<<<dim3(24, 24, 18), dim3(32, 8), 0, stream>>>(wfc, wpj, w1, w2, Wt);
    router_kernel<<<N_TOK / 4, 256, 0, stream>>>(x, rw, bias, topk_w, eids);
    bucketize_kernel<<<E_NUM, 1024, 0, stream>>>(eids, counts, buckets);

    gemm256_kernel<0><<<dim3(N_TOK / 256, C_DIM / 256, E_NUM + 1), 512, 0, stream>>>(
        xb, xb, Wt, Hsh, H, counts, buckets);
    gemm256_kernel<1><<<dim3(N_TOK / 256, C_DIM / 256, E_NUM + 1), 512, 0, stream>>>(
        Hsh, H, Wt, out, Y, counts, buckets);

    combine_kernel<<<(N_TOK * (C_DIM / 4) + 255) / 256, 256, 0, stream>>>(out, Y, topk_w);
}

// Round 5
// 171.501 us; speedup vs baseline: 1.6589x; 1.6589x over previous
//
#include <hip/hip_runtime.h>
#include <stdint.h>

#define N_TOK 8192
#define C_DIM 768
#define E_NUM 8
#define TOTX 200              // 136 expert x-blocks max + 64 shared
#define GRID1 1200            // TOTX * 6 column-tiles
#define CHUNK 150             // GRID1 / 8 XCDs

typedef short short8 __attribute__((ext_vector_type(8)));
typedef __bf16 bf16x8 __attribute__((ext_vector_type(8)));
typedef float f32x4 __attribute__((ext_vector_type(4)));

static __device__ __forceinline__ unsigned short f2bf(float f) {
    unsigned u = __float_as_uint(f);
    unsigned r = u + 0x7FFFu + ((u >> 16) & 1u);
    return (unsigned short)(r >> 16);
}
static __device__ __forceinline__ float bf2f(unsigned short h) {
    return __uint_as_float(((unsigned)h) << 16);
}

// ------------- transpose+convert weights: Wt[m][o][i] = W[m][i][o], bf16 -------------
__global__ void wtrans_kernel(const float* __restrict__ wfc, const float* __restrict__ wpj,
                              const float* __restrict__ w1, const float* __restrict__ w2,
                              unsigned short* __restrict__ Wt) {
    __shared__ float tile[32][33];
    const int m = blockIdx.z;
    const float* src = (m == 0) ? wfc : (m == 1) ? wpj
                     : (m < 10) ? (w1 + (size_t)(m - 2) * C_DIM * C_DIM)
                                : (w2 + (size_t)(m - 10) * C_DIM * C_DIM);
    const int i0 = blockIdx.y * 32;
    const int o0 = blockIdx.x * 32;
    #pragma unroll
    for (int rr = 0; rr < 32; rr += 8)
        tile[threadIdx.y + rr][threadIdx.x] = src[(size_t)(i0 + threadIdx.y + rr) * C_DIM + o0 + threadIdx.x];
    __syncthreads();
    unsigned short* dst = Wt + (size_t)m * C_DIM * C_DIM;
    #pragma unroll
    for (int rr = 0; rr < 32; rr += 8) {
        int o = o0 + threadIdx.y + rr;
        dst[(size_t)o * C_DIM + i0 + threadIdx.x] = f2bf(tile[threadIdx.x][threadIdx.y + rr]);
    }
}

// ---- router pass 1: fp32 logits, sigmoid, top-2 (no atomics); also emits xb = bf16(x) ----
__global__ void router_kernel(const float* __restrict__ x, const float* __restrict__ rw,
                              const float* __restrict__ bias,
                              float* __restrict__ topk_w, int* __restrict__ eids,
                              unsigned short* __restrict__ xb) {
    const int wave = threadIdx.x >> 6;
    const int lane = threadIdx.x & 63;
    const int n = blockIdx.x * 4 + wave;
    const float* xp = x + (size_t)n * C_DIM + lane * 12;
    float xv[12];
    #pragma unroll
    for (int j = 0; j < 12; j++) xv[j] = xp[j];
    // fused fp32 -> bf16 conversion of x
    unsigned short* xbp = xb + (size_t)n * C_DIM + lane * 12;
    #pragma unroll
    for (int j = 0; j < 12; j++) xbp[j] = f2bf(xv[j]);
    float acc[E_NUM];
    #pragma unroll
    for (int e = 0; e < E_NUM; e++) acc[e] = 0.f;
    #pragma unroll
    for (int e = 0; e < E_NUM; e++) {
        const float* wp = rw + (size_t)e * C_DIM + lane * 12;
        #pragma unroll
        for (int j = 0; j < 12; j++) acc[e] += xv[j] * wp[j];
    }
    #pragma unroll
    for (int e = 0; e < E_NUM; e++) {
        #pragma unroll
        for (int off = 32; off > 0; off >>= 1) acc[e] += __shfl_xor(acc[e], off, 64);
    }
    if (lane == 0) {
        float sc[E_NUM];
        #pragma unroll
        for (int e = 0; e < E_NUM; e++) sc[e] = 1.f / (1.f + expf(-acc[e]));
        int e0 = 0; float best = -1e30f;
        #pragma unroll
        for (int e = 0; e < E_NUM; e++) { float v = sc[e] + bias[e]; if (v > best) { best = v; e0 = e; } }
        int e1 = -1; float best1 = -1e30f;
        #pragma unroll
        for (int e = 0; e < E_NUM; e++) { if (e == e0) continue; float v = sc[e] + bias[e]; if (v > best1) { best1 = v; e1 = e; } }
        float w0 = sc[e0], w1 = sc[e1];
        float s = w0 + w1 + 1e-20f;
        w0 /= s; w1 /= s;
        topk_w[n * 2] = w0; topk_w[n * 2 + 1] = w1;
        eids[n * 2] = e0; eids[n * 2 + 1] = e1;
    }
}

// ---------------- router pass 2: per-expert compaction (deterministic) ----------------
__global__ __launch_bounds__(1024) void bucketize_kernel(const int* __restrict__ eids,
                                                         int* __restrict__ counts,
                                                         int* __restrict__ buckets) {
    const int e = blockIdx.x;
    const int t = threadIdx.x;
    const int wv = t >> 6, lane = t & 63;
    __shared__ int wave_tot[16];
    int running = 0;
    for (int start = 0; start < 2 * N_TOK; start += 1024) {
        const int i = start + t;
        const int f = (eids[i] == e) ? 1 : 0;
        unsigned long long mask = __ballot(f);
        int pre = __popcll(mask & ((1ull << lane) - 1ull));
        if (lane == 0) wave_tot[wv] = __popcll(mask);
        __syncthreads();
        int wbase = 0, tot = 0;
        #pragma unroll
        for (int j = 0; j < 16; j++) { int c = wave_tot[j]; tot += c; if (j < wv) wbase += c; }
        if (f) buckets[e * N_TOK + running + wbase + pre] = i;
        running += tot;
        __syncthreads();
    }
    if (t == 0) counts[e] = running;
}

// -------- block-offset prefix table: xoffs[z] = first x-block of expert z; [8]=shared start --------
__global__ void prefix_kernel(const int* __restrict__ counts, int* __restrict__ xoffs) {
    if (threadIdx.x == 0 && blockIdx.x == 0) {
        int a = 0;
        for (int z = 0; z < E_NUM; z++) { xoffs[z] = a; a += (counts[z] + 127) >> 7; }
        xoffs[E_NUM] = a;            // shared starts here
        xoffs[E_NUM + 1] = a + 64;   // end of work
    }
}

// ---------------- merged bf16 MFMA GEMM (dense compacted grid + XCD chunk swizzle) ----------------
// PHASE 0 (fc):   A = xb (shared direct; expert gather token=ent>>1); epi relu^2 -> Hsh[n] / H[ent]
// PHASE 1 (proj): A = Hsh (shared) / H gathered by ent (expert);      epi -> out[n] fp32 / Y[ent]
// LDS swizzle (zero-conflict, verified r3): 16B slot' = slot ^ ((row>>1)&3); linear gload_lds dest +
// pre-swizzled global source + swizzled ds_read.
#define GLOAD_LDS(g, l) __builtin_amdgcn_global_load_lds((const __attribute__((address_space(1))) void*)(g), (__attribute__((address_space(3))) void*)(l), 16, 0, 0)

template <int PHASE>
__global__ __launch_bounds__(256) void gemm_all_kernel(const unsigned short* __restrict__ Adir,
                                                       const unsigned short* __restrict__ Agat,
                                                       const unsigned short* __restrict__ WtAll,
                                                       void* __restrict__ dstDir,
                                                       unsigned short* __restrict__ dstGat,
                                                       const int* __restrict__ counts,
                                                       const int* __restrict__ buckets,
                                                       const int* __restrict__ xoffs) {
    // XCD chunk swizzle (bijective: GRID1 = 8 * CHUNK)
    const int fid = blockIdx.x;
    const int swz = (fid & 7) * CHUNK + (fid >> 3);
    const int y = swz / TOTX;
    const int xx = swz - y * TOTX;
    int xo[10];
    #pragma unroll
    for (int i = 0; i < 10; i++) xo[i] = xoffs[i];
    if (xx >= xo[9]) return;
    int z = E_NUM, xl = xx - xo[8];
    #pragma unroll
    for (int zz = 0; zz < E_NUM; zz++)
        if (xx >= xo[zz] && xx < xo[zz + 1]) { z = zz; xl = xx - xo[zz]; }
    const bool sh = (z == E_NUM);
    const int rows = sh ? N_TOK : counts[z];
    const int r0 = xl * 128;
    const int c0 = y * 128;

    __shared__ __align__(16) unsigned short As[128 * 32];
    __shared__ __align__(16) unsigned short Bs[128 * 32];

    const int t = threadIdx.x;
    const int lane = t & 63;
    const int wv = t >> 6;
    const int wr = (wv >> 1) * 64;
    const int wc = (wv & 1) * 64;

    const int widx = sh ? (PHASE == 0 ? 0 : 1) : (PHASE == 0 ? 2 + z : 10 + z);
    const unsigned short* Bmat = WtAll + (size_t)widx * C_DIM * C_DIM;
    const int* bk = buckets + z * N_TOK;

    // staging: thread t -> LDS rows (t>>2, 64+(t>>2)), LDS 16B slot t&3 (linear dest),
    // global slot pre-swizzled: (t&3) ^ ((row>>1)&3), (row>>1)&3 == (t>>3)&3
    const int ar0 = t >> 2;
    const int ar1 = 64 + (t >> 2);
    const int acol = (((t & 3) ^ ((t >> 3) & 3)) * 8);
    int grow0, grow1;
    const unsigned short* Asrc;
    if (sh) {
        Asrc = Adir;
        grow0 = r0 + ar0; grow1 = r0 + ar1;
    } else {
        Asrc = Agat;
        int p0 = r0 + ar0, p1 = r0 + ar1;
        int e0v = bk[p0 < rows ? p0 : 0];
        int e1v = bk[p1 < rows ? p1 : 0];
        grow0 = (PHASE == 0) ? (e0v >> 1) : e0v;
        grow1 = (PHASE == 0) ? (e1v >> 1) : e1v;
    }
    const unsigned short* aptr0 = Asrc + (size_t)grow0 * C_DIM + acol;
    const unsigned short* aptr1 = Asrc + (size_t)grow1 * C_DIM + acol;
    const unsigned short* bptr0 = Bmat + (size_t)(c0 + ar0) * C_DIM + acol;
    const unsigned short* bptr1 = Bmat + (size_t)(c0 + ar1) * C_DIM + acol;

    char* ldsA = (char*)&As[0];
    char* ldsB = (char*)&Bs[0];

    f32x4 acc[4][4];
    #pragma unroll
    for (int i = 0; i < 4; i++)
        #pragma unroll
        for (int j = 0; j < 4; j++) acc[i][j] = (f32x4){0.f, 0.f, 0.f, 0.f};

    // fragment-read LDS slot: (lane>>4) ^ ((row>>1)&3), row bits from lane
    const int qr = (((lane >> 4) ^ ((lane >> 1) & 3)) * 8);

    for (int kt = 0; kt < C_DIM / 32; ++kt) {
        if (kt) __syncthreads();
        const int ko = kt * 32;
        GLOAD_LDS(aptr0 + ko, ldsA + t * 16);
        GLOAD_LDS(aptr1 + ko, ldsA + 4096 + t * 16);
        GLOAD_LDS(bptr0 + ko, ldsB + t * 16);
        GLOAD_LDS(bptr1 + ko, ldsB + 4096 + t * 16);
        __syncthreads();

        short8 af[4], bfr[4];
        #pragma unroll
        for (int i = 0; i < 4; i++)
            af[i] = *reinterpret_cast<const short8*>(&As[(size_t)(wr + i * 16 + (lane & 15)) * 32 + qr]);
        #pragma unroll
        for (int j = 0; j < 4; j++)
            bfr[j] = *reinterpret_cast<const short8*>(&Bs[(size_t)(wc + j * 16 + (lane & 15)) * 32 + qr]);
        #pragma unroll
        for (int i = 0; i < 4; i++)
            #pragma unroll
            for (int j = 0; j < 4; j++)
                acc[i][j] = __builtin_amdgcn_mfma_f32_16x16x32_bf16(
                    __builtin_bit_cast(bf16x8, af[i]), __builtin_bit_cast(bf16x8, bfr[j]), acc[i][j], 0, 0, 0);
    }

    const int fr = lane & 15;
    const int fq = lane >> 4;
    if (sh) {
        if constexpr (PHASE == 0) {
            unsigned short* Hd = (unsigned short*)dstDir;
            #pragma unroll
            for (int i = 0; i < 4; i++)
                #pragma unroll
                for (int rr = 0; rr < 4; rr++) {
                    int n = r0 + wr + i * 16 + fq * 4 + rr;
                    size_t base = (size_t)n * C_DIM;
                    #pragma unroll
                    for (int j = 0; j < 4; j++) {
                        int col = c0 + wc + j * 16 + fr;
                        float v = acc[i][j][rr];
                        float rl = v > 0.f ? v : 0.f;
                        Hd[base + col] = f2bf(rl * rl);
                    }
                }
        } else {
            float* od = (float*)dstDir;
            #pragma unroll
            for (int i = 0; i < 4; i++)
                #pragma unroll
                for (int rr = 0; rr < 4; rr++) {
                    int n = r0 + wr + i * 16 + fq * 4 + rr;
                    size_t base = (size_t)n * C_DIM;
                    #pragma unroll
                    for (int j = 0; j < 4; j++) {
                        int col = c0 + wc + j * 16 + fr;
                        od[base + col] = acc[i][j][rr];
                    }
                }
        }
    } else {
        #pragma unroll
        for (int i = 0; i < 4; i++)
            #pragma unroll
            for (int rr = 0; rr < 4; rr++) {
                int pos = r0 + wr + i * 16 + fq * 4 + rr;
                if (pos < rows) {
                    int ent = bk[pos];
                    size_t base = (size_t)ent * C_DIM;
                    #pragma unroll
                    for (int j = 0; j < 4; j++) {
                        int col = c0 + wc + j * 16 + fr;
                        float v = acc[i][j][rr];
                        if (PHASE == 0) {
                            float rl = v > 0.f ? v : 0.f;
                            dstGat[base + col] = f2bf(rl * rl);
                        } else {
                            dstGat[base + col] = f2bf(v);
                        }
                    }
                }
            }
    }
}

// ---------------- combine: out += w0*Y[n,0] + w1*Y[n,1] ----------------
__global__ void combine_kernel(float* __restrict__ out, const unsigned short* __restrict__ Y,
                               const float* __restrict__ tw) {
    int idx = blockIdx.x * blockDim.x + threadIdx.x;
    const int per_row = C_DIM / 4;
    if (idx >= N_TOK * per_row) return;
    int n = idx / per_row;
    int c = (idx % per_row) * 4;
    float w0 = tw[n * 2], w1 = tw[n * 2 + 1];
    const ushort4 a = *reinterpret_cast<const ushort4*>(Y + (size_t)(n * 2) * C_DIM + c);
    const ushort4 b = *reinterpret_cast<const ushort4*>(Y + (size_t)(n * 2 + 1) * C_DIM + c);
    float4* op = reinterpret_cast<float4*>(out + (size_t)n * C_DIM + c);
    float4 o = *op;
    o.x += w0 * bf2f(a.x) + w1 * bf2f(b.x);
    o.y += w0 * bf2f(a.y) + w1 * bf2f(b.y);
    o.z += w0 * bf2f(a.z) + w1 * bf2f(b.z);
    o.w += w0 * bf2f(a.w) + w1 * bf2f(b.w);
    *op = o;
}

extern "C" void kernel_launch(void* const* d_in, const int* in_sizes, int n_in,
                              void* d_out, int out_size, void* d_ws, size_t ws_size,
                              hipStream_t stream) {
    const float* x   = (const float*)d_in[0];
    const float* wfc = (const float*)d_in[1];
    const float* wpj = (const float*)d_in[2];
    const float* w1  = (const float*)d_in[3];
    const float* w2  = (const float*)d_in[4];
    const float* rw  = (const float*)d_in[5];
    const float* bias= (const float*)d_in[6];
    float* out = (float*)d_out;

    char* ws = (char*)d_ws;
    size_t off = 0;
    auto alloc = [&](size_t bytes) { void* p = ws + off; off += (bytes + 255) & ~(size_t)255; return p; };
    unsigned short* xb   = (unsigned short*)alloc((size_t)N_TOK * C_DIM * 2);
    unsigned short* Wt   = (unsigned short*)alloc((size_t)18 * C_DIM * C_DIM * 2);
    unsigned short* H    = (unsigned short*)alloc((size_t)N_TOK * 2 * C_DIM * 2);  // expert hidden, by entry
    unsigned short* Hsh  = (unsigned short*)alloc((size_t)N_TOK * C_DIM * 2);      // shared hidden
    unsigned short* Y    = (unsigned short*)alloc((size_t)N_TOK * 2 * C_DIM * 2);  // expert out, by entry
    float* topk_w        = (float*)alloc((size_t)N_TOK * 2 * 4);
    int* counts          = (int*)alloc(256);
    int* buckets         = (int*)alloc((size_t)E_NUM * N_TOK * 4);
    int* eids            = (int*)alloc((size_t)2 * N_TOK * 4);
    int* xoffs           = (int*)alloc(64);

    wtrans_kernel<<<dim3(24, 24, 18), dim3(32, 8), 0, stream>>>(wfc, wpj, w1, w2, Wt);
    router_kernel<<<N_TOK / 4, 256, 0, stream>>>(x, rw, bias, topk_w, eids, xb);
    bucketize_kernel<<<E_NUM, 1024, 0, stream>>>(eids, counts, buckets);
    prefix_kernel<<<1, 64, 0, stream>>>(counts, xoffs);

    gemm_all_kernel<0><<<GRID1, 256, 0, stream>>>(xb, xb, Wt, Hsh, H, counts, buckets, xoffs);
    gemm_all_kernel<1><<<GRID1, 256, 0, stream>>>(Hsh, H, Wt, out, Y, counts, buckets, xoffs);

    combine_kernel<<<(N_TOK * (C_DIM / 4) + 255) / 256, 256, 0, stream>>>(out, Y, topk_w);
}

// Round 6
// 158.900 us; speedup vs baseline: 1.7905x; 1.0793x over previous
//
#include <hip/hip_runtime.h>
#include <stdint.h>

#define N_TOK 8192
#define C_DIM 768
#define E_NUM 8
#define NT (C_DIM / 32)       // 24 K-tiles
#define TOTX 200              // 136 expert x-blocks max + 64 shared
#define GRID1 1200            // TOTX * 6 column-tiles
#define CHUNK 150             // GRID1 / 8 XCDs

typedef short short8 __attribute__((ext_vector_type(8)));
typedef __bf16 bf16x8 __attribute__((ext_vector_type(8)));
typedef float f32x4 __attribute__((ext_vector_type(4)));

static __device__ __forceinline__ unsigned short f2bf(float f) {
    unsigned u = __float_as_uint(f);
    unsigned r = u + 0x7FFFu + ((u >> 16) & 1u);
    return (unsigned short)(r >> 16);
}
static __device__ __forceinline__ float bf2f(unsigned short h) {
    return __uint_as_float(((unsigned)h) << 16);
}

// ------------- transpose+convert weights: Wt[m][o][i] = W[m][i][o], bf16 -------------
__global__ void wtrans_kernel(const float* __restrict__ wfc, const float* __restrict__ wpj,
                              const float* __restrict__ w1, const float* __restrict__ w2,
                              unsigned short* __restrict__ Wt) {
    __shared__ float tile[32][33];
    const int m = blockIdx.z;
    const float* src = (m == 0) ? wfc : (m == 1) ? wpj
                     : (m < 10) ? (w1 + (size_t)(m - 2) * C_DIM * C_DIM)
                                : (w2 + (size_t)(m - 10) * C_DIM * C_DIM);
    const int i0 = blockIdx.y * 32;
    const int o0 = blockIdx.x * 32;
    #pragma unroll
    for (int rr = 0; rr < 32; rr += 8)
        tile[threadIdx.y + rr][threadIdx.x] = src[(size_t)(i0 + threadIdx.y + rr) * C_DIM + o0 + threadIdx.x];
    __syncthreads();
    unsigned short* dst = Wt + (size_t)m * C_DIM * C_DIM;
    #pragma unroll
    for (int rr = 0; rr < 32; rr += 8) {
        int o = o0 + threadIdx.y + rr;
        dst[(size_t)o * C_DIM + i0 + threadIdx.x] = f2bf(tile[threadIdx.x][threadIdx.y + rr]);
    }
}

// ---- router pass 1: fp32 logits, sigmoid, top-2 (no atomics); also emits xb = bf16(x) ----
__global__ void router_kernel(const float* __restrict__ x, const float* __restrict__ rw,
                              const float* __restrict__ bias,
                              float* __restrict__ topk_w, int* __restrict__ eids,
                              unsigned short* __restrict__ xb) {
    const int wave = threadIdx.x >> 6;
    const int lane = threadIdx.x & 63;
    const int n = blockIdx.x * 4 + wave;
    const float* xp = x + (size_t)n * C_DIM + lane * 12;
    float xv[12];
    #pragma unroll
    for (int j = 0; j < 12; j++) xv[j] = xp[j];
    unsigned short* xbp = xb + (size_t)n * C_DIM + lane * 12;
    #pragma unroll
    for (int j = 0; j < 12; j++) xbp[j] = f2bf(xv[j]);
    float acc[E_NUM];
    #pragma unroll
    for (int e = 0; e < E_NUM; e++) acc[e] = 0.f;
    #pragma unroll
    for (int e = 0; e < E_NUM; e++) {
        const float* wp = rw + (size_t)e * C_DIM + lane * 12;
        #pragma unroll
        for (int j = 0; j < 12; j++) acc[e] += xv[j] * wp[j];
    }
    #pragma unroll
    for (int e = 0; e < E_NUM; e++) {
        #pragma unroll
        for (int off = 32; off > 0; off >>= 1) acc[e] += __shfl_xor(acc[e], off, 64);
    }
    if (lane == 0) {
        float sc[E_NUM];
        #pragma unroll
        for (int e = 0; e < E_NUM; e++) sc[e] = 1.f / (1.f + expf(-acc[e]));
        int e0 = 0; float best = -1e30f;
        #pragma unroll
        for (int e = 0; e < E_NUM; e++) { float v = sc[e] + bias[e]; if (v > best) { best = v; e0 = e; } }
        int e1 = -1; float best1 = -1e30f;
        #pragma unroll
        for (int e = 0; e < E_NUM; e++) { if (e == e0) continue; float v = sc[e] + bias[e]; if (v > best1) { best1 = v; e1 = e; } }
        float w0 = sc[e0], w1 = sc[e1];
        float s = w0 + w1 + 1e-20f;
        w0 /= s; w1 /= s;
        topk_w[n * 2] = w0; topk_w[n * 2 + 1] = w1;
        eids[n * 2] = e0; eids[n * 2 + 1] = e1;
    }
}

// ---------------- router pass 2: per-expert compaction (deterministic) ----------------
__global__ __launch_bounds__(1024) void bucketize_kernel(const int* __restrict__ eids,
                                                         int* __restrict__ counts,
                                                         int* __restrict__ buckets) {
    const int e = blockIdx.x;
    const int t = threadIdx.x;
    const int wv = t >> 6, lane = t & 63;
    __shared__ int wave_tot[16];
    int running = 0;
    for (int start = 0; start < 2 * N_TOK; start += 1024) {
        const int i = start + t;
        const int f = (eids[i] == e) ? 1 : 0;
        unsigned long long mask = __ballot(f);
        int pre = __popcll(mask & ((1ull << lane) - 1ull));
        if (lane == 0) wave_tot[wv] = __popcll(mask);
        __syncthreads();
        int wbase = 0, tot = 0;
        #pragma unroll
        for (int j = 0; j < 16; j++) { int c = wave_tot[j]; tot += c; if (j < wv) wbase += c; }
        if (f) buckets[e * N_TOK + running + wbase + pre] = i;
        running += tot;
        __syncthreads();
    }
    if (t == 0) counts[e] = running;
}

// -------- block-offset prefix table: xoffs[z] = first x-block of expert z; [8]=shared start --------
__global__ void prefix_kernel(const int* __restrict__ counts, int* __restrict__ xoffs) {
    if (threadIdx.x == 0 && blockIdx.x == 0) {
        int a = 0;
        for (int z = 0; z < E_NUM; z++) { xoffs[z] = a; a += (counts[z] + 127) >> 7; }
        xoffs[E_NUM] = a;            // shared starts here
        xoffs[E_NUM + 1] = a + 64;   // end of work
    }
}

// ------- merged bf16 MFMA GEMM: compacted grid + XCD swizzle + depth-3 LDS ring, counted vmcnt ----
// PHASE 0 (fc):   A = xb (shared direct; expert gather token=ent>>1); epi relu^2 -> Hsh[n] / H[ent]
// PHASE 1 (proj): A = Hsh (shared) / H gathered by ent (expert);      epi -> out[n] fp32 / Y[ent]
// LDS: 3 buffers x 16 KiB (A 128x32 @0, B 128x32 @4096 ushorts). Ring: STAGE(kt+2) then vmcnt(8)
// (never 0 until tail). Swizzle (zero-conflict, verified r3): 16B slot' = slot ^ ((row>>1)&3);
// linear gload_lds dest + pre-swizzled global source + swizzled ds_read.
#define GLOAD_LDS(g, l) __builtin_amdgcn_global_load_lds((const __attribute__((address_space(1))) void*)(g), (__attribute__((address_space(3))) void*)(l), 16, 0, 0)
#define WAITVM(n) asm volatile("s_waitcnt vmcnt(" #n ")" ::: "memory")
#define SCHEDB() __builtin_amdgcn_sched_barrier(0)
#define BAR() __builtin_amdgcn_s_barrier()

template <int PHASE>
__global__ __launch_bounds__(256) void gemm_all_kernel(const unsigned short* __restrict__ Adir,
                                                       const unsigned short* __restrict__ Agat,
                                                       const unsigned short* __restrict__ WtAll,
                                                       void* __restrict__ dstDir,
                                                       unsigned short* __restrict__ dstGat,
                                                       const int* __restrict__ counts,
                                                       const int* __restrict__ buckets,
                                                       const int* __restrict__ xoffs) {
    // XCD chunk swizzle (bijective: GRID1 = 8 * CHUNK)
    const int fid = blockIdx.x;
    const int swz = (fid & 7) * CHUNK + (fid >> 3);
    const int y = swz / TOTX;
    const int xx = swz - y * TOTX;
    int xo[10];
    #pragma unroll
    for (int i = 0; i < 10; i++) xo[i] = xoffs[i];
    if (xx >= xo[9]) return;
    int z = E_NUM, xl = xx - xo[8];
    #pragma unroll
    for (int zz = 0; zz < E_NUM; zz++)
        if (xx >= xo[zz] && xx < xo[zz + 1]) { z = zz; xl = xx - xo[zz]; }
    const bool sh = (z == E_NUM);
    const int rows = sh ? N_TOK : counts[z];
    const int r0 = xl * 128;
    const int c0 = y * 128;

    __shared__ __align__(16) unsigned short lds[3 * 8192];   // 48 KiB ring

    const int t = threadIdx.x;
    const int lane = t & 63;
    const int wv = t >> 6;
    const int wr = (wv >> 1) * 64;
    const int wc = (wv & 1) * 64;

    const int widx = sh ? (PHASE == 0 ? 0 : 1) : (PHASE == 0 ? 2 + z : 10 + z);
    const unsigned short* Bmat = WtAll + (size_t)widx * C_DIM * C_DIM;
    const int* bk = buckets + z * N_TOK;

    // staging: thread t -> LDS rows (t>>2, 64+(t>>2)), 16B slot t&3 (linear dest),
    // global slot pre-swizzled: (t&3) ^ ((row>>1)&3), (row>>1)&3 == (t>>3)&3
    const int ar0 = t >> 2;
    const int ar1 = 64 + (t >> 2);
    const int acol = (((t & 3) ^ ((t >> 3) & 3)) * 8);
    int grow0, grow1;
    const unsigned short* Asrc;
    if (sh) {
        Asrc = Adir;
        grow0 = r0 + ar0; grow1 = r0 + ar1;
    } else {
        Asrc = Agat;
        int p0 = r0 + ar0, p1 = r0 + ar1;
        int e0v = bk[p0 < rows ? p0 : 0];
        int e1v = bk[p1 < rows ? p1 : 0];
        grow0 = (PHASE == 0) ? (e0v >> 1) : e0v;
        grow1 = (PHASE == 0) ? (e1v >> 1) : e1v;
    }
    const unsigned short* aptr0 = Asrc + (size_t)grow0 * C_DIM + acol;
    const unsigned short* aptr1 = Asrc + (size_t)grow1 * C_DIM + acol;
    const unsigned short* bptr0 = Bmat + (size_t)(c0 + ar0) * C_DIM + acol;
    const unsigned short* bptr1 = Bmat + (size_t)(c0 + ar1) * C_DIM + acol;

    f32x4 acc[4][4];
    #pragma unroll
    for (int i = 0; i < 4; i++)
        #pragma unroll
        for (int j = 0; j < 4; j++) acc[i][j] = (f32x4){0.f, 0.f, 0.f, 0.f};

    // fragment-read LDS slot: (lane>>4) ^ ((row>>1)&3), row bits from lane
    const int qr = (((lane >> 4) ^ ((lane >> 1) & 3)) * 8);

    // prologue: stage tiles 0 and 1 into buffers 0 and 1 (8 vm-ops outstanding per wave)
    {
        unsigned short* d0 = lds + t * 8;
        GLOAD_LDS(aptr0, d0);
        GLOAD_LDS(aptr1, d0 + 2048);
        GLOAD_LDS(bptr0, d0 + 4096);
        GLOAD_LDS(bptr1, d0 + 6144);
        unsigned short* d1 = lds + 8192 + t * 8;
        GLOAD_LDS(aptr0 + 32, d1);
        GLOAD_LDS(aptr1 + 32, d1 + 2048);
        GLOAD_LDS(bptr0 + 32, d1 + 4096);
        GLOAD_LDS(bptr1 + 32, d1 + 6144);
    }

    #pragma unroll
    for (int kt = 0; kt < NT; ++kt) {
        if (kt + 2 < NT) {
            // stage tile kt+2 into buffer (kt+2)%3, then wait for tile kt (leave 8 in flight)
            unsigned short* d = lds + ((kt + 2) % 3) * 8192 + t * 8;
            const int ko = (kt + 2) * 32;
            GLOAD_LDS(aptr0 + ko, d);
            GLOAD_LDS(aptr1 + ko, d + 2048);
            GLOAD_LDS(bptr0 + ko, d + 4096);
            GLOAD_LDS(bptr1 + ko, d + 6144);
            WAITVM(8);
        } else if (kt + 2 == NT) {
            WAITVM(4);
        } else {
            WAITVM(0);
        }
        BAR();          // tile kt present in LDS for all waves
        SCHEDB();
        const unsigned short* buf = lds + (kt % 3) * 8192;
        short8 af[4], bfr[4];
        #pragma unroll
        for (int i = 0; i < 4; i++)
            af[i] = *reinterpret_cast<const short8*>(buf + (size_t)(wr + i * 16 + (lane & 15)) * 32 + qr);
        #pragma unroll
        for (int j = 0; j < 4; j++)
            bfr[j] = *reinterpret_cast<const short8*>(buf + 4096 + (size_t)(wc + j * 16 + (lane & 15)) * 32 + qr);
        __builtin_amdgcn_s_setprio(1);
        #pragma unroll
        for (int i = 0; i < 4; i++)
            #pragma unroll
            for (int j = 0; j < 4; j++)
                acc[i][j] = __builtin_amdgcn_mfma_f32_16x16x32_bf16(
                    __builtin_bit_cast(bf16x8, af[i]), __builtin_bit_cast(bf16x8, bfr[j]), acc[i][j], 0, 0, 0);
        __builtin_amdgcn_s_setprio(0);
        SCHEDB();
        BAR();          // all waves done reading buf[kt%3]; safe to overwrite at iter kt+1's stage
    }

    const int fr = lane & 15;
    const int fq = lane >> 4;
    if (sh) {
        if constexpr (PHASE == 0) {
            unsigned short* Hd = (unsigned short*)dstDir;
            #pragma unroll
            for (int i = 0; i < 4; i++)
                #pragma unroll
                for (int rr = 0; rr < 4; rr++) {
                    int n = r0 + wr + i * 16 + fq * 4 + rr;
                    size_t base = (size_t)n * C_DIM;
                    #pragma unroll
                    for (int j = 0; j < 4; j++) {
                        int col = c0 + wc + j * 16 + fr;
                        float v = acc[i][j][rr];
                        float rl = v > 0.f ? v : 0.f;
                        Hd[base + col] = f2bf(rl * rl);
                    }
                }
        } else {
            float* od = (float*)dstDir;
            #pragma unroll
            for (int i = 0; i < 4; i++)
                #pragma unroll
                for (int rr = 0; rr < 4; rr++) {
                    int n = r0 + wr + i * 16 + fq * 4 + rr;
                    size_t base = (size_t)n * C_DIM;
                    #pragma unroll
                    for (int j = 0; j < 4; j++) {
                        int col = c0 + wc + j * 16 + fr;
                        od[base + col] = acc[i][j][rr];
                    }
                }
        }
    } else {
        #pragma unroll
        for (int i = 0; i < 4; i++)
            #pragma unroll
            for (int rr = 0; rr < 4; rr++) {
                int pos = r0 + wr + i * 16 + fq * 4 + rr;
                if (pos < rows) {
                    int ent = bk[pos];
                    size_t base = (size_t)ent * C_DIM;
                    #pragma unroll
                    for (int j = 0; j < 4; j++) {
                        int col = c0 + wc + j * 16 + fr;
                        float v = acc[i][j][rr];
                        if (PHASE == 0) {
                            float rl = v > 0.f ? v : 0.f;
                            dstGat[base + col] = f2bf(rl * rl);
                        } else {
                            dstGat[base + col] = f2bf(v);
                        }
                    }
                }
            }
    }
}

// ---------------- combine: out += w0*Y[n,0] + w1*Y[n,1] ----------------
__global__ void combine_kernel(float* __restrict__ out, const unsigned short* __restrict__ Y,
                               const float* __restrict__ tw) {
    int idx = blockIdx.x * blockDim.x + threadIdx.x;
    const int per_row = C_DIM / 4;
    if (idx >= N_TOK * per_row) return;
    int n = idx / per_row;
    int c = (idx % per_row) * 4;
    float w0 = tw[n * 2], w1 = tw[n * 2 + 1];
    const ushort4 a = *reinterpret_cast<const ushort4*>(Y + (size_t)(n * 2) * C_DIM + c);
    const ushort4 b = *reinterpret_cast<const ushort4*>(Y + (size_t)(n * 2 + 1) * C_DIM + c);
    float4* op = reinterpret_cast<float4*>(out + (size_t)n * C_DIM + c);
    float4 o = *op;
    o.x += w0 * bf2f(a.x) + w1 * bf2f(b.x);
    o.y += w0 * bf2f(a.y) + w1 * bf2f(b.y);
    o.z += w0 * bf2f(a.z) + w1 * bf2f(b.z);
    o.w += w0 * bf2f(a.w) + w1 * bf2f(b.w);
    *op = o;
}

extern "C" void kernel_launch(void* const* d_in, const int* in_sizes, int n_in,
                              void* d_out, int out_size, void* d_ws, size_t ws_size,
                              hipStream_t stream) {
    const float* x   = (const float*)d_in[0];
    const float* wfc = (const float*)d_in[1];
    const float* wpj = (const float*)d_in[2];
    const float* w1  = (const float*)d_in[3];
    const float* w2  = (const float*)d_in[4];
    const float* rw  = (const float*)d_in[5];
    const float* bias= (const float*)d_in[6];
    float* out = (float*)d_out;

    char* ws = (char*)d_ws;
    size_t off = 0;
    auto alloc = [&](size_t bytes) { void* p = ws + off; off += (bytes + 255) & ~(size_t)255; return p; };
    unsigned short* xb   = (unsigned short*)alloc((size_t)N_TOK * C_DIM * 2);
    unsigned short* Wt   = (unsigned short*)alloc((size_t)18 * C_DIM * C_DIM * 2);
    unsigned short* H    = (unsigned short*)alloc((size_t)N_TOK * 2 * C_DIM * 2);  // expert hidden, by entry
    unsigned short* Hsh  = (unsigned short*)alloc((size_t)N_TOK * C_DIM * 2);      // shared hidden
    unsigned short* Y    = (unsigned short*)alloc((size_t)N_TOK * 2 * C_DIM * 2);  // expert out, by entry
    float* topk_w        = (float*)alloc((size_t)N_TOK * 2 * 4);
    int* counts          = (int*)alloc(256);
    int* buckets         = (int*)alloc((size_t)E_NUM * N_TOK * 4);
    int* eids            = (int*)alloc((size_t)2 * N_TOK * 4);
    int* xoffs           = (int*)alloc(64);

    wtrans_kernel<<<dim3(24, 24, 18), dim3(32, 8), 0, stream>>>(wfc, wpj, w1, w2, Wt);
    router_kernel<<<N_TOK / 4, 256, 0, stream>>>(x, rw, bias, topk_w, eids, xb);
    bucketize_kernel<<<E_NUM, 1024, 0, stream>>>(eids, counts, buckets);
    prefix_kernel<<<1, 64, 0, stream>>>(counts, xoffs);

    gemm_all_kernel<0><<<GRID1, 256, 0, stream>>>(xb, xb, Wt, Hsh, H, counts, buckets, xoffs);
    gemm_all_kernel<1><<<GRID1, 256, 0, stream>>>(Hsh, H, Wt, out, Y, counts, buckets, xoffs);

    combine_kernel<<<(N_TOK * (C_DIM / 4) + 255) / 256, 256, 0, stream>>>(out, Y, topk_w);
}

// Round 7
// 145.509 us; speedup vs baseline: 1.9553x; 1.0920x over previous
//
#include <hip/hip_runtime.h>
#include <stdint.h>

#define N_TOK 8192
#define C_DIM 768
#define E_NUM 8
#define NT (C_DIM / 32)       // 24 K-tiles
#define TOTX 200              // 136 expert x-blocks max + 64 shared
#define GRID1 1200            // TOTX * 6 column-tiles
#define XXPX 25               // xx-values per XCD (200/8)

typedef short short8 __attribute__((ext_vector_type(8)));
typedef __bf16 bf16x8 __attribute__((ext_vector_type(8)));
typedef float f32x4 __attribute__((ext_vector_type(4)));

static __device__ __forceinline__ unsigned short f2bf(float f) {
    unsigned u = __float_as_uint(f);
    unsigned r = u + 0x7FFFu + ((u >> 16) & 1u);
    return (unsigned short)(r >> 16);
}
static __device__ __forceinline__ float bf2f(unsigned short h) {
    return __uint_as_float(((unsigned)h) << 16);
}

// ------------- transpose+convert weights: Wt[m][o][i] = W[m][i][o], bf16 -------------
__global__ void wtrans_kernel(const float* __restrict__ wfc, const float* __restrict__ wpj,
                              const float* __restrict__ w1, const float* __restrict__ w2,
                              unsigned short* __restrict__ Wt) {
    __shared__ float tile[32][33];
    const int m = blockIdx.z;
    const float* src = (m == 0) ? wfc : (m == 1) ? wpj
                     : (m < 10) ? (w1 + (size_t)(m - 2) * C_DIM * C_DIM)
                                : (w2 + (size_t)(m - 10) * C_DIM * C_DIM);
    const int i0 = blockIdx.y * 32;
    const int o0 = blockIdx.x * 32;
    #pragma unroll
    for (int rr = 0; rr < 32; rr += 8)
        tile[threadIdx.y + rr][threadIdx.x] = src[(size_t)(i0 + threadIdx.y + rr) * C_DIM + o0 + threadIdx.x];
    __syncthreads();
    unsigned short* dst = Wt + (size_t)m * C_DIM * C_DIM;
    #pragma unroll
    for (int rr = 0; rr < 32; rr += 8) {
        int o = o0 + threadIdx.y + rr;
        dst[(size_t)o * C_DIM + i0 + threadIdx.x] = f2bf(tile[threadIdx.x][threadIdx.y + rr]);
    }
}

// ---- router pass 1: fp32 logits, sigmoid, top-2 (no atomics); also emits xb = bf16(x) ----
__global__ void router_kernel(const float* __restrict__ x, const float* __restrict__ rw,
                              const float* __restrict__ bias,
                              float* __restrict__ topk_w, int* __restrict__ eids,
                              unsigned short* __restrict__ xb) {
    const int wave = threadIdx.x >> 6;
    const int lane = threadIdx.x & 63;
    const int n = blockIdx.x * 4 + wave;
    const float* xp = x + (size_t)n * C_DIM + lane * 12;
    float xv[12];
    #pragma unroll
    for (int j = 0; j < 12; j++) xv[j] = xp[j];
    unsigned short* xbp = xb + (size_t)n * C_DIM + lane * 12;
    #pragma unroll
    for (int j = 0; j < 12; j++) xbp[j] = f2bf(xv[j]);
    float acc[E_NUM];
    #pragma unroll
    for (int e = 0; e < E_NUM; e++) acc[e] = 0.f;
    #pragma unroll
    for (int e = 0; e < E_NUM; e++) {
        const float* wp = rw + (size_t)e * C_DIM + lane * 12;
        #pragma unroll
        for (int j = 0; j < 12; j++) acc[e] += xv[j] * wp[j];
    }
    #pragma unroll
    for (int e = 0; e < E_NUM; e++) {
        #pragma unroll
        for (int off = 32; off > 0; off >>= 1) acc[e] += __shfl_xor(acc[e], off, 64);
    }
    if (lane == 0) {
        float sc[E_NUM];
        #pragma unroll
        for (int e = 0; e < E_NUM; e++) sc[e] = 1.f / (1.f + expf(-acc[e]));
        int e0 = 0; float best = -1e30f;
        #pragma unroll
        for (int e = 0; e < E_NUM; e++) { float v = sc[e] + bias[e]; if (v > best) { best = v; e0 = e; } }
        int e1 = -1; float best1 = -1e30f;
        #pragma unroll
        for (int e = 0; e < E_NUM; e++) { if (e == e0) continue; float v = sc[e] + bias[e]; if (v > best1) { best1 = v; e1 = e; } }
        float w0 = sc[e0], w1 = sc[e1];
        float s = w0 + w1 + 1e-20f;
        w0 /= s; w1 /= s;
        topk_w[n * 2] = w0; topk_w[n * 2 + 1] = w1;
        eids[n * 2] = e0; eids[n * 2 + 1] = e1;
    }
}

// ---------------- router pass 2: per-expert compaction (deterministic) ----------------
__global__ __launch_bounds__(1024) void bucketize_kernel(const int* __restrict__ eids,
                                                         int* __restrict__ counts,
                                                         int* __restrict__ buckets) {
    const int e = blockIdx.x;
    const int t = threadIdx.x;
    const int wv = t >> 6, lane = t & 63;
    __shared__ int wave_tot[16];
    int running = 0;
    for (int start = 0; start < 2 * N_TOK; start += 1024) {
        const int i = start + t;
        const int f = (eids[i] == e) ? 1 : 0;
        unsigned long long mask = __ballot(f);
        int pre = __popcll(mask & ((1ull << lane) - 1ull));
        if (lane == 0) wave_tot[wv] = __popcll(mask);
        __syncthreads();
        int wbase = 0, tot = 0;
        #pragma unroll
        for (int j = 0; j < 16; j++) { int c = wave_tot[j]; tot += c; if (j < wv) wbase += c; }
        if (f) buckets[e * N_TOK + running + wbase + pre] = i;
        running += tot;
        __syncthreads();
    }
    if (t == 0) counts[e] = running;
}

// -------- block-offset prefix table: xoffs[z] = first x-block of expert z; [8]=shared start --------
__global__ void prefix_kernel(const int* __restrict__ counts, int* __restrict__ xoffs) {
    if (threadIdx.x == 0 && blockIdx.x == 0) {
        int a = 0;
        for (int z = 0; z < E_NUM; z++) { xoffs[z] = a; a += (counts[z] + 127) >> 7; }
        xoffs[E_NUM] = a;            // shared starts here
        xoffs[E_NUM + 1] = a + 64;   // end of work
    }
}

// ------- merged bf16 MFMA GEMM: L2-locality swizzle + depth-4 ring, single barrier/K-step ----
// PHASE 0 (fc):   A = xb (shared direct; expert gather token=ent>>1); epi relu^2 -> Hsh[n] / H[ent]
// PHASE 1 (proj): A = Hsh (shared) / H gathered by ent (expert);      epi -> out[n] fp32 / Y[ent]
// Swizzle: xcd = fid&7 owns xx in [xcd*25, xcd*25+25), y innermost -> the 6 blocks sharing an
// A-panel are adjacent on one XCD (A L2-reuse x6); same-expert B-panels stay L2-resident.
// LDS: 4 buffers x 16 KiB ring (A 128x32 @0, B 128x32 @4096 ushorts). Single s_barrier per step:
// safe because STAGE(kt+2) in window (BAR(kt-1),BAR(kt)) only reuses the buffer of tile kt-2,
// whose reads completed before each reader arrived at BAR(kt-1). vmcnt(8) steady state.
// LDS bank swizzle (zero-conflict, verified r3): 16B slot' = slot ^ ((row>>1)&3).
#define GLOAD_LDS(g, l) __builtin_amdgcn_global_load_lds((const __attribute__((address_space(1))) void*)(g), (__attribute__((address_space(3))) void*)(l), 16, 0, 0)
#define WAITVM(n) asm volatile("s_waitcnt vmcnt(" #n ")" ::: "memory")
#define SCHEDB() __builtin_amdgcn_sched_barrier(0)
#define BAR() __builtin_amdgcn_s_barrier()

template <int PHASE>
__global__ __launch_bounds__(256) void gemm_all_kernel(const unsigned short* __restrict__ Adir,
                                                       const unsigned short* __restrict__ Agat,
                                                       const unsigned short* __restrict__ WtAll,
                                                       void* __restrict__ dstDir,
                                                       unsigned short* __restrict__ dstGat,
                                                       const int* __restrict__ counts,
                                                       const int* __restrict__ buckets,
                                                       const int* __restrict__ xoffs) {
    // L2-locality decode: xcd-contiguous xx, y innermost
    const int fid = blockIdx.x;
    const int xcd = fid & 7;
    const int i6 = fid >> 3;              // 0..149
    const int xx = xcd * XXPX + i6 / 6;
    const int y = i6 % 6;
    int xo[10];
    #pragma unroll
    for (int i = 0; i < 10; i++) xo[i] = xoffs[i];
    if (xx >= xo[9]) return;
    int z = E_NUM, xl = xx - xo[8];
    #pragma unroll
    for (int zz = 0; zz < E_NUM; zz++)
        if (xx >= xo[zz] && xx < xo[zz + 1]) { z = zz; xl = xx - xo[zz]; }
    const bool sh = (z == E_NUM);
    const int rows = sh ? N_TOK : counts[z];
    const int r0 = xl * 128;
    const int c0 = y * 128;

    __shared__ __align__(16) unsigned short lds[4 * 8192];   // 64 KiB ring

    const int t = threadIdx.x;
    const int lane = t & 63;
    const int wv = t >> 6;
    const int wr = (wv >> 1) * 64;
    const int wc = (wv & 1) * 64;

    const int widx = sh ? (PHASE == 0 ? 0 : 1) : (PHASE == 0 ? 2 + z : 10 + z);
    const unsigned short* Bmat = WtAll + (size_t)widx * C_DIM * C_DIM;
    const int* bk = buckets + z * N_TOK;

    // staging: thread t -> LDS rows (t>>2, 64+(t>>2)), 16B slot t&3 (linear dest),
    // global slot pre-swizzled: (t&3) ^ ((row>>1)&3), (row>>1)&3 == (t>>3)&3
    const int ar0 = t >> 2;
    const int ar1 = 64 + (t >> 2);
    const int acol = (((t & 3) ^ ((t >> 3) & 3)) * 8);
    int grow0, grow1;
    const unsigned short* Asrc;
    if (sh) {
        Asrc = Adir;
        grow0 = r0 + ar0; grow1 = r0 + ar1;
    } else {
        Asrc = Agat;
        int p0 = r0 + ar0, p1 = r0 + ar1;
        int e0v = bk[p0 < rows ? p0 : 0];
        int e1v = bk[p1 < rows ? p1 : 0];
        grow0 = (PHASE == 0) ? (e0v >> 1) : e0v;
        grow1 = (PHASE == 0) ? (e1v >> 1) : e1v;
    }
    const unsigned short* aptr0 = Asrc + (size_t)grow0 * C_DIM + acol;
    const unsigned short* aptr1 = Asrc + (size_t)grow1 * C_DIM + acol;
    const unsigned short* bptr0 = Bmat + (size_t)(c0 + ar0) * C_DIM + acol;
    const unsigned short* bptr1 = Bmat + (size_t)(c0 + ar1) * C_DIM + acol;

    f32x4 acc[4][4];
    #pragma unroll
    for (int i = 0; i < 4; i++)
        #pragma unroll
        for (int j = 0; j < 4; j++) acc[i][j] = (f32x4){0.f, 0.f, 0.f, 0.f};

    // fragment-read LDS slot: (lane>>4) ^ ((row>>1)&3), row bits from lane
    const int qr = (((lane >> 4) ^ ((lane >> 1) & 3)) * 8);

    // prologue: stage tiles 0 and 1 into buffers 0 and 1 (8 vm-ops outstanding per wave)
    {
        unsigned short* d0 = lds + t * 8;
        GLOAD_LDS(aptr0, d0);
        GLOAD_LDS(aptr1, d0 + 2048);
        GLOAD_LDS(bptr0, d0 + 4096);
        GLOAD_LDS(bptr1, d0 + 6144);
        unsigned short* d1 = lds + 8192 + t * 8;
        GLOAD_LDS(aptr0 + 32, d1);
        GLOAD_LDS(aptr1 + 32, d1 + 2048);
        GLOAD_LDS(bptr0 + 32, d1 + 4096);
        GLOAD_LDS(bptr1 + 32, d1 + 6144);
    }

    #pragma unroll
    for (int kt = 0; kt < NT; ++kt) {
        if (kt + 2 < NT) {
            // stage tile kt+2 into buffer (kt+2)%4, then wait for tile kt (leave 8 in flight)
            unsigned short* d = lds + ((kt + 2) & 3) * 8192 + t * 8;
            const int ko = (kt + 2) * 32;
            GLOAD_LDS(aptr0 + ko, d);
            GLOAD_LDS(aptr1 + ko, d + 2048);
            GLOAD_LDS(bptr0 + ko, d + 4096);
            GLOAD_LDS(bptr1 + ko, d + 6144);
            WAITVM(8);
        } else if (kt + 2 == NT) {
            WAITVM(4);
        } else {
            WAITVM(0);
        }
        BAR();          // tile kt present in LDS for all waves
        SCHEDB();       // nothing may hoist above this barrier
        const unsigned short* buf = lds + (kt & 3) * 8192;
        short8 af[4], bfr[4];
        #pragma unroll
        for (int i = 0; i < 4; i++)
            af[i] = *reinterpret_cast<const short8*>(buf + (size_t)(wr + i * 16 + (lane & 15)) * 32 + qr);
        #pragma unroll
        for (int j = 0; j < 4; j++)
            bfr[j] = *reinterpret_cast<const short8*>(buf + 4096 + (size_t)(wc + j * 16 + (lane & 15)) * 32 + qr);
        __builtin_amdgcn_s_setprio(1);
        #pragma unroll
        for (int i = 0; i < 4; i++)
            #pragma unroll
            for (int j = 0; j < 4; j++)
                acc[i][j] = __builtin_amdgcn_mfma_f32_16x16x32_bf16(
                    __builtin_bit_cast(bf16x8, af[i]), __builtin_bit_cast(bf16x8, bfr[j]), acc[i][j], 0, 0, 0);
        __builtin_amdgcn_s_setprio(0);
        // no trailing barrier: depth-4 ring makes next stage target a buffer whose readers
        // all completed before they arrived at the barrier above.
    }

    const int fr = lane & 15;
    const int fq = lane >> 4;
    if (sh) {
        if constexpr (PHASE == 0) {
            unsigned short* Hd = (unsigned short*)dstDir;
            #pragma unroll
            for (int i = 0; i < 4; i++)
                #pragma unroll
                for (int rr = 0; rr < 4; rr++) {
                    int n = r0 + wr + i * 16 + fq * 4 + rr;
                    size_t base = (size_t)n * C_DIM;
                    #pragma unroll
                    for (int j = 0; j < 4; j++) {
                        int col = c0 + wc + j * 16 + fr;
                        float v = acc[i][j][rr];
                        float rl = v > 0.f ? v : 0.f;
                        Hd[base + col] = f2bf(rl * rl);
                    }
                }
        } else {
            float* od = (float*)dstDir;
            #pragma unroll
            for (int i = 0; i < 4; i++)
                #pragma unroll
                for (int rr = 0; rr < 4; rr++) {
                    int n = r0 + wr + i * 16 + fq * 4 + rr;
                    size_t base = (size_t)n * C_DIM;
                    #pragma unroll
                    for (int j = 0; j < 4; j++) {
                        int col = c0 + wc + j * 16 + fr;
                        od[base + col] = acc[i][j][rr];
                    }
                }
        }
    } else {
        #pragma unroll
        for (int i = 0; i < 4; i++)
            #pragma unroll
            for (int rr = 0; rr < 4; rr++) {
                int pos = r0 + wr + i * 16 + fq * 4 + rr;
                if (pos < rows) {
                    int ent = bk[pos];
                    size_t base = (size_t)ent * C_DIM;
                    #pragma unroll
                    for (int j = 0; j < 4; j++) {
                        int col = c0 + wc + j * 16 + fr;
                        float v = acc[i][j][rr];
                        if (PHASE == 0) {
                            float rl = v > 0.f ? v : 0.f;
                            dstGat[base + col] = f2bf(rl * rl);
                        } else {
                            dstGat[base + col] = f2bf(v);
                        }
                    }
                }
            }
    }
}

// ---------------- combine: out += w0*Y[n,0] + w1*Y[n,1] ----------------
__global__ void combine_kernel(float* __restrict__ out, const unsigned short* __restrict__ Y,
                               const float* __restrict__ tw) {
    int idx = blockIdx.x * blockDim.x + threadIdx.x;
    const int per_row = C_DIM / 4;
    if (idx >= N_TOK * per_row) return;
    int n = idx / per_row;
    int c = (idx % per_row) * 4;
    float w0 = tw[n * 2], w1 = tw[n * 2 + 1];
    const ushort4 a = *reinterpret_cast<const ushort4*>(Y + (size_t)(n * 2) * C_DIM + c);
    const ushort4 b = *reinterpret_cast<const ushort4*>(Y + (size_t)(n * 2 + 1) * C_DIM + c);
    float4* op = reinterpret_cast<float4*>(out + (size_t)n * C_DIM + c);
    float4 o = *op;
    o.x += w0 * bf2f(a.x) + w1 * bf2f(b.x);
    o.y += w0 * bf2f(a.y) + w1 * bf2f(b.y);
    o.z += w0 * bf2f(a.z) + w1 * bf2f(b.z);
    o.w += w0 * bf2f(a.w) + w1 * bf2f(b.w);
    *op = o;
}

extern "C" void kernel_launch(void* const* d_in, const int* in_sizes, int n_in,
                              void* d_out, int out_size, void* d_ws, size_t ws_size,
                              hipStream_t stream) {
    const float* x   = (const float*)d_in[0];
    const float* wfc = (const float*)d_in[1];
    const float* wpj = (const float*)d_in[2];
    const float* w1  = (const float*)d_in[3];
    const float* w2  = (const float*)d_in[4];
    const float* rw  = (const float*)d_in[5];
    const float* bias= (const float*)d_in[6];
    float* out = (float*)d_out;

    char* ws = (char*)d_ws;
    size_t off = 0;
    auto alloc = [&](size_t bytes) { void* p = ws + off; off += (bytes + 255) & ~(size_t)255; return p; };
    unsigned short* xb   = (unsigned short*)alloc((size_t)N_TOK * C_DIM * 2);
    unsigned short* Wt   = (unsigned short*)alloc((size_t)18 * C_DIM * C_DIM * 2);
    unsigned short* H    = (unsigned short*)alloc((size_t)N_TOK * 2 * C_DIM * 2);  // expert hidden, by entry
    unsigned short* Hsh  = (unsigned short*)alloc((size_t)N_TOK * C_DIM * 2);      // shared hidden
    unsigned short* Y    = (unsigned short*)alloc((size_t)N_TOK * 2 * C_DIM * 2);  // expert out, by entry
    float* topk_w        = (float*)alloc((size_t)N_TOK * 2 * 4);
    int* counts          = (int*)alloc(256);
    int* buckets         = (int*)alloc((size_t)E_NUM * N_TOK * 4);
    int* eids            = (int*)alloc((size_t)2 * N_TOK * 4);
    int* xoffs           = (int*)alloc(64);

    wtrans_kernel<<<dim3(24, 24, 18), dim3(32, 8), 0, stream>>>(wfc, wpj, w1, w2, Wt);
    router_kernel<<<N_TOK / 4, 256, 0, stream>>>(x, rw, bias, topk_w, eids, xb);
    bucketize_kernel<<<E_NUM, 1024, 0, stream>>>(eids, counts, buckets);
    prefix_kernel<<<1, 64, 0, stream>>>(counts, xoffs);

    gemm_all_kernel<0><<<GRID1, 256, 0, stream>>>(xb, xb, Wt, Hsh, H, counts, buckets, xoffs);
    gemm_all_kernel<1><<<GRID1, 256, 0, stream>>>(Hsh, H, Wt, out, Y, counts, buckets, xoffs);

    combine_kernel<<<(N_TOK * (C_DIM / 4) + 255) / 256, 256, 0, stream>>>(out, Y, topk_w);
}

// Round 8
// 140.162 us; speedup vs baseline: 2.0299x; 1.0382x over previous
//
#include <hip/hip_runtime.h>
#include <stdint.h>

#define N_TOK 8192
#define C_DIM 768
#define E_NUM 8
#define NT2 (C_DIM / 64)      // 12 K-tiles of 64
#define TOTX 200              // 136 expert x-blocks max + 64 shared
#define GRID1 1200            // TOTX * 6 column-tiles
#define XXPX 25               // xx-values per XCD (200/8)

typedef short short8 __attribute__((ext_vector_type(8)));
typedef __bf16 bf16x8 __attribute__((ext_vector_type(8)));
typedef float f32x4 __attribute__((ext_vector_type(4)));

static __device__ __forceinline__ unsigned short f2bf(float f) {
    unsigned u = __float_as_uint(f);
    unsigned r = u + 0x7FFFu + ((u >> 16) & 1u);
    return (unsigned short)(r >> 16);
}
static __device__ __forceinline__ float bf2f(unsigned short h) {
    return __uint_as_float(((unsigned)h) << 16);
}

// ------------- transpose+convert weights: Wt[m][o][i] = W[m][i][o], bf16 -------------
__global__ void wtrans_kernel(const float* __restrict__ wfc, const float* __restrict__ wpj,
                              const float* __restrict__ w1, const float* __restrict__ w2,
                              unsigned short* __restrict__ Wt) {
    __shared__ float tile[32][33];
    const int m = blockIdx.z;
    const float* src = (m == 0) ? wfc : (m == 1) ? wpj
                     : (m < 10) ? (w1 + (size_t)(m - 2) * C_DIM * C_DIM)
                                : (w2 + (size_t)(m - 10) * C_DIM * C_DIM);
    const int i0 = blockIdx.y * 32;
    const int o0 = blockIdx.x * 32;
    #pragma unroll
    for (int rr = 0; rr < 32; rr += 8)
        tile[threadIdx.y + rr][threadIdx.x] = src[(size_t)(i0 + threadIdx.y + rr) * C_DIM + o0 + threadIdx.x];
    __syncthreads();
    unsigned short* dst = Wt + (size_t)m * C_DIM * C_DIM;
    #pragma unroll
    for (int rr = 0; rr < 32; rr += 8) {
        int o = o0 + threadIdx.y + rr;
        dst[(size_t)o * C_DIM + i0 + threadIdx.x] = f2bf(tile[threadIdx.x][threadIdx.y + rr]);
    }
}

// ---- router pass 1: fp32 logits, sigmoid, top-2 (no atomics); also emits xb = bf16(x) ----
__global__ void router_kernel(const float* __restrict__ x, const float* __restrict__ rw,
                              const float* __restrict__ bias,
                              float* __restrict__ topk_w, int* __restrict__ eids,
                              unsigned short* __restrict__ xb) {
    const int wave = threadIdx.x >> 6;
    const int lane = threadIdx.x & 63;
    const int n = blockIdx.x * 4 + wave;
    const float* xp = x + (size_t)n * C_DIM + lane * 12;
    float xv[12];
    #pragma unroll
    for (int j = 0; j < 12; j++) xv[j] = xp[j];
    unsigned short* xbp = xb + (size_t)n * C_DIM + lane * 12;
    #pragma unroll
    for (int j = 0; j < 12; j++) xbp[j] = f2bf(xv[j]);
    float acc[E_NUM];
    #pragma unroll
    for (int e = 0; e < E_NUM; e++) acc[e] = 0.f;
    #pragma unroll
    for (int e = 0; e < E_NUM; e++) {
        const float* wp = rw + (size_t)e * C_DIM + lane * 12;
        #pragma unroll
        for (int j = 0; j < 12; j++) acc[e] += xv[j] * wp[j];
    }
    #pragma unroll
    for (int e = 0; e < E_NUM; e++) {
        #pragma unroll
        for (int off = 32; off > 0; off >>= 1) acc[e] += __shfl_xor(acc[e], off, 64);
    }
    if (lane == 0) {
        float sc[E_NUM];
        #pragma unroll
        for (int e = 0; e < E_NUM; e++) sc[e] = 1.f / (1.f + expf(-acc[e]));
        int e0 = 0; float best = -1e30f;
        #pragma unroll
        for (int e = 0; e < E_NUM; e++) { float v = sc[e] + bias[e]; if (v > best) { best = v; e0 = e; } }
        int e1 = -1; float best1 = -1e30f;
        #pragma unroll
        for (int e = 0; e < E_NUM; e++) { if (e == e0) continue; float v = sc[e] + bias[e]; if (v > best1) { best1 = v; e1 = e; } }
        float w0 = sc[e0], w1 = sc[e1];
        float s = w0 + w1 + 1e-20f;
        w0 /= s; w1 /= s;
        topk_w[n * 2] = w0; topk_w[n * 2 + 1] = w1;
        eids[n * 2] = e0; eids[n * 2 + 1] = e1;
    }
}

// ---------------- router pass 2: per-expert compaction (deterministic) ----------------
__global__ __launch_bounds__(1024) void bucketize_kernel(const int* __restrict__ eids,
                                                         int* __restrict__ counts,
                                                         int* __restrict__ buckets) {
    const int e = blockIdx.x;
    const int t = threadIdx.x;
    const int wv = t >> 6, lane = t & 63;
    __shared__ int wave_tot[16];
    int running = 0;
    for (int start = 0; start < 2 * N_TOK; start += 1024) {
        const int i = start + t;
        const int f = (eids[i] == e) ? 1 : 0;
        unsigned long long mask = __ballot(f);
        int pre = __popcll(mask & ((1ull << lane) - 1ull));
        if (lane == 0) wave_tot[wv] = __popcll(mask);
        __syncthreads();
        int wbase = 0, tot = 0;
        #pragma unroll
        for (int j = 0; j < 16; j++) { int c = wave_tot[j]; tot += c; if (j < wv) wbase += c; }
        if (f) buckets[e * N_TOK + running + wbase + pre] = i;
        running += tot;
        __syncthreads();
    }
    if (t == 0) counts[e] = running;
}

// -------- block-offset prefix table: xoffs[z] = first x-block of expert z; [8]=shared start --------
__global__ void prefix_kernel(const int* __restrict__ counts, int* __restrict__ xoffs) {
    if (threadIdx.x == 0 && blockIdx.x == 0) {
        int a = 0;
        for (int z = 0; z < E_NUM; z++) { xoffs[z] = a; a += (counts[z] + 127) >> 7; }
        xoffs[E_NUM] = a;            // shared starts here
        xoffs[E_NUM + 1] = a + 64;   // end of work
    }
}

// ------- merged bf16 MFMA GEMM: L2 swizzle + BK=64 double-buffer, 1 barrier/K-step ----
// PHASE 0 (fc):   A = xb (shared direct; expert gather token=ent>>1); epi relu^2 -> Hsh[n] / H[ent]
// PHASE 1 (proj): A = Hsh (shared) / H gathered by ent (expert);      epi -> out[n] fp32 / Y[ent]
// Grid: xcd = fid&7 owns xx in [xcd*25, +25), y innermost -> A-panel L2-reuse x6 per XCD.
// BK=64: each row segment = 128 B (full line); stage instr = 8 rows x 128 B fully coalesced.
// LDS: 2 x 32 KiB double buffer (A 128x64 @0, B 128x64 @8192 ushorts).
// Schedule per step: WAITVM(0) [issued a full compute-phase earlier]; BAR; stage(kt+1) into the
// other buffer (its prior readers provably passed BAR(kt)); ds_read+32 MFMA on tile kt.
// Bank swizzle: 16B slot' = slot ^ (row&7) -> full 32-bank spread, 2-way max (free).
#define GLOAD_LDS(g, l) __builtin_amdgcn_global_load_lds((const __attribute__((address_space(1))) void*)(g), (__attribute__((address_space(3))) void*)(l), 16, 0, 0)
#define WAITVM0() asm volatile("s_waitcnt vmcnt(0)" ::: "memory")
#define SCHEDB() __builtin_amdgcn_sched_barrier(0)
#define BAR() __builtin_amdgcn_s_barrier()

template <int PHASE>
__global__ __launch_bounds__(256, 2) void gemm_all_kernel(const unsigned short* __restrict__ Adir,
                                                          const unsigned short* __restrict__ Agat,
                                                          const unsigned short* __restrict__ WtAll,
                                                          void* __restrict__ dstDir,
                                                          unsigned short* __restrict__ dstGat,
                                                          const int* __restrict__ counts,
                                                          const int* __restrict__ buckets,
                                                          const int* __restrict__ xoffs) {
    // L2-locality decode: xcd-contiguous xx, y innermost
    const int fid = blockIdx.x;
    const int xcd = fid & 7;
    const int i6 = fid >> 3;              // 0..149
    const int xx = xcd * XXPX + i6 / 6;
    const int y = i6 % 6;
    int xo[10];
    #pragma unroll
    for (int i = 0; i < 10; i++) xo[i] = xoffs[i];
    if (xx >= xo[9]) return;
    int z = E_NUM, xl = xx - xo[8];
    #pragma unroll
    for (int zz = 0; zz < E_NUM; zz++)
        if (xx >= xo[zz] && xx < xo[zz + 1]) { z = zz; xl = xx - xo[zz]; }
    const bool sh = (z == E_NUM);
    const int rows = sh ? N_TOK : counts[z];
    const int r0 = xl * 128;
    const int c0 = y * 128;

    __shared__ __align__(16) unsigned short lds[2 * 16384];   // 64 KiB double buffer

    const int t = threadIdx.x;
    const int lane = t & 63;
    const int wv = t >> 6;
    const int wr = (wv >> 1) * 64;
    const int wc = (wv & 1) * 64;

    const int widx = sh ? (PHASE == 0 ? 0 : 1) : (PHASE == 0 ? 2 + z : 10 + z);
    const unsigned short* Bmat = WtAll + (size_t)widx * C_DIM * C_DIM;
    const int* bk = buckets + z * N_TOK;

    // staging: thread t covers rows 32c + (t>>3) (c=0..3), 16B slot t&7 (linear dest t*8 ushorts),
    // global slot pre-swizzled: (t&7) ^ (row&7), row&7 == (t>>3)&7 (chunk adds 32, keeps &7)
    const int srow = t >> 3;                                     // 0..31
    const int scol = (((t & 7) ^ ((t >> 3) & 7)) * 8);           // pre-swizzled source col (elems)
    int grow[4];
    const unsigned short* Asrc;
    if (sh) {
        Asrc = Adir;
        #pragma unroll
        for (int c = 0; c < 4; c++) grow[c] = r0 + 32 * c + srow;
    } else {
        Asrc = Agat;
        #pragma unroll
        for (int c = 0; c < 4; c++) {
            int p = r0 + 32 * c + srow;
            int ev = bk[p < rows ? p : 0];
            grow[c] = (PHASE == 0) ? (ev >> 1) : ev;
        }
    }
    const unsigned short* ap[4];
    const unsigned short* bp[4];
    #pragma unroll
    for (int c = 0; c < 4; c++) {
        ap[c] = Asrc + (size_t)grow[c] * C_DIM + scol;
        bp[c] = Bmat + (size_t)(c0 + 32 * c + srow) * C_DIM + scol;
    }

    f32x4 acc[4][4];
    #pragma unroll
    for (int i = 0; i < 4; i++)
        #pragma unroll
        for (int j = 0; j < 4; j++) acc[i][j] = (f32x4){0.f, 0.f, 0.f, 0.f};

    // fragment-read swizzled k-slot (elems): slot = kk*4+fq, row&7 = fr&7
    const int fr = lane & 15;
    const int fq = lane >> 4;
    const int ks0 = ((fq ^ (fr & 7)) * 8);
    const int ks1 = (((4 + fq) ^ (fr & 7)) * 8);

    // prologue: stage tile 0 into buffer 0 (8 vm-ops per thread)
    {
        unsigned short* d = lds + t * 8;
        #pragma unroll
        for (int c = 0; c < 4; c++) {
            GLOAD_LDS(ap[c], d + c * 2048);
            GLOAD_LDS(bp[c], d + 8192 + c * 2048);
        }
    }

    #pragma unroll
    for (int kt = 0; kt < NT2; ++kt) {
        WAITVM0();      // tile kt's loads (issued one full compute-phase ago) complete
        BAR();          // tile kt visible to all waves; prior readers of other buffer done
        SCHEDB();
        if (kt + 1 < NT2) {
            unsigned short* d = lds + ((kt + 1) & 1) * 16384 + t * 8;
            const int ko = (kt + 1) * 64;
            #pragma unroll
            for (int c = 0; c < 4; c++) {
                GLOAD_LDS(ap[c] + ko, d + c * 2048);
                GLOAD_LDS(bp[c] + ko, d + 8192 + c * 2048);
            }
        }
        SCHEDB();       // stage issued before compute; compute may not hoist above
        const unsigned short* buf = lds + (kt & 1) * 16384;
        short8 af[4][2], bfr[4][2];
        #pragma unroll
        for (int i = 0; i < 4; i++) {
            const unsigned short* rp = buf + (size_t)(wr + i * 16 + fr) * 64;
            af[i][0] = *reinterpret_cast<const short8*>(rp + ks0);
            af[i][1] = *reinterpret_cast<const short8*>(rp + ks1);
        }
        #pragma unroll
        for (int j = 0; j < 4; j++) {
            const unsigned short* rp = buf + 8192 + (size_t)(wc + j * 16 + fr) * 64;
            bfr[j][0] = *reinterpret_cast<const short8*>(rp + ks0);
            bfr[j][1] = *reinterpret_cast<const short8*>(rp + ks1);
        }
        __builtin_amdgcn_s_setprio(1);
        #pragma unroll
        for (int kk = 0; kk < 2; kk++)
            #pragma unroll
            for (int i = 0; i < 4; i++)
                #pragma unroll
                for (int j = 0; j < 4; j++)
                    acc[i][j] = __builtin_amdgcn_mfma_f32_16x16x32_bf16(
                        __builtin_bit_cast(bf16x8, af[i][kk]), __builtin_bit_cast(bf16x8, bfr[j][kk]),
                        acc[i][j], 0, 0, 0);
        __builtin_amdgcn_s_setprio(0);
        // single barrier per step: next iteration's stage targets the buffer whose readers
        // all passed this step's BAR before it was overwritten.
    }

    if (sh) {
        if constexpr (PHASE == 0) {
            unsigned short* Hd = (unsigned short*)dstDir;
            #pragma unroll
            for (int i = 0; i < 4; i++)
                #pragma unroll
                for (int rr = 0; rr < 4; rr++) {
                    int n = r0 + wr + i * 16 + fq * 4 + rr;
                    size_t base = (size_t)n * C_DIM;
                    #pragma unroll
                    for (int j = 0; j < 4; j++) {
                        int col = c0 + wc + j * 16 + fr;
                        float v = acc[i][j][rr];
                        float rl = v > 0.f ? v : 0.f;
                        Hd[base + col] = f2bf(rl * rl);
                    }
                }
        } else {
            float* od = (float*)dstDir;
            #pragma unroll
            for (int i = 0; i < 4; i++)
                #pragma unroll
                for (int rr = 0; rr < 4; rr++) {
                    int n = r0 + wr + i * 16 + fq * 4 + rr;
                    size_t base = (size_t)n * C_DIM;
                    #pragma unroll
                    for (int j = 0; j < 4; j++) {
                        int col = c0 + wc + j * 16 + fr;
                        od[base + col] = acc[i][j][rr];
                    }
                }
        }
    } else {
        #pragma unroll
        for (int i = 0; i < 4; i++)
            #pragma unroll
            for (int rr = 0; rr < 4; rr++) {
                int pos = r0 + wr + i * 16 + fq * 4 + rr;
                if (pos < rows) {
                    int ent = bk[pos];
                    size_t base = (size_t)ent * C_DIM;
                    #pragma unroll
                    for (int j = 0; j < 4; j++) {
                        int col = c0 + wc + j * 16 + fr;
                        float v = acc[i][j][rr];
                        if (PHASE == 0) {
                            float rl = v > 0.f ? v : 0.f;
                            dstGat[base + col] = f2bf(rl * rl);
                        } else {
                            dstGat[base + col] = f2bf(v);
                        }
                    }
                }
            }
    }
}

// ---------------- combine: out += w0*Y[n,0] + w1*Y[n,1] ----------------
__global__ void combine_kernel(float* __restrict__ out, const unsigned short* __restrict__ Y,
                               const float* __restrict__ tw) {
    int idx = blockIdx.x * blockDim.x + threadIdx.x;
    const int per_row = C_DIM / 4;
    if (idx >= N_TOK * per_row) return;
    int n = idx / per_row;
    int c = (idx % per_row) * 4;
    float w0 = tw[n * 2], w1 = tw[n * 2 + 1];
    const ushort4 a = *reinterpret_cast<const ushort4*>(Y + (size_t)(n * 2) * C_DIM + c);
    const ushort4 b = *reinterpret_cast<const ushort4*>(Y + (size_t)(n * 2 + 1) * C_DIM + c);
    float4* op = reinterpret_cast<float4*>(out + (size_t)n * C_DIM + c);
    float4 o = *op;
    o.x += w0 * bf2f(a.x) + w1 * bf2f(b.x);
    o.y += w0 * bf2f(a.y) + w1 * bf2f(b.y);
    o.z += w0 * bf2f(a.z) + w1 * bf2f(b.z);
    o.w += w0 * bf2f(a.w) + w1 * bf2f(b.w);
    *op = o;
}

extern "C" void kernel_launch(void* const* d_in, const int* in_sizes, int n_in,
                              void* d_out, int out_size, void* d_ws, size_t ws_size,
                              hipStream_t stream) {
    const float* x   = (const float*)d_in[0];
    const float* wfc = (const float*)d_in[1];
    const float* wpj = (const float*)d_in[2];
    const float* w1  = (const float*)d_in[3];
    const float* w2  = (const float*)d_in[4];
    const float* rw  = (const float*)d_in[5];
    const float* bias= (const float*)d_in[6];
    float* out = (float*)d_out;

    char* ws = (char*)d_ws;
    size_t off = 0;
    auto alloc = [&](size_t bytes) { void* p = ws + off; off += (bytes + 255) & ~(size_t)255; return p; };
    unsigned short* xb   = (unsigned short*)alloc((size_t)N_TOK * C_DIM * 2);
    unsigned short* Wt   = (unsigned short*)alloc((size_t)18 * C_DIM * C_DIM * 2);
    unsigned short* H    = (unsigned short*)alloc((size_t)N_TOK * 2 * C_DIM * 2);  // expert hidden, by entry
    unsigned short* Hsh  = (unsigned short*)alloc((size_t)N_TOK * C_DIM * 2);      // shared hidden
    unsigned short* Y    = (unsigned short*)alloc((size_t)N_TOK * 2 * C_DIM * 2);  // expert out, by entry
    float* topk_w        = (float*)alloc((size_t)N_TOK * 2 * 4);
    int* counts          = (int*)alloc(256);
    int* buckets         = (int*)alloc((size_t)E_NUM * N_TOK * 4);
    int* eids            = (int*)alloc((size_t)2 * N_TOK * 4);
    int* xoffs           = (int*)alloc(64);

    wtrans_kernel<<<dim3(24, 24, 18), dim3(32, 8), 0, stream>>>(wfc, wpj, w1, w2, Wt);
    router_kernel<<<N_TOK / 4, 256, 0, stream>>>(x, rw, bias, topk_w, eids, xb);
    bucketize_kernel<<<E_NUM, 1024, 0, stream>>>(eids, counts, buckets);
    prefix_kernel<<<1, 64, 0, stream>>>(counts, xoffs);

    gemm_all_kernel<0><<<GRID1, 256, 0, stream>>>(xb, xb, Wt, Hsh, H, counts, buckets, xoffs);
    gemm_all_kernel<1><<<GRID1, 256, 0, stream>>>(Hsh, H, Wt, out, Y, counts, buckets, xoffs);

    combine_kernel<<<(N_TOK * (C_DIM / 4) + 255) / 256, 256, 0, stream>>>(out, Y, topk_w);
}